// Round 8
// baseline (228.421 us; speedup 1.0000x reference)
//
#include <hip/hip_runtime.h>
#include <stdint.h>

// Problem constants (from reference setup_inputs)
constexpr int B  = 32;
constexpr int H  = 256;
constexpr int W  = 1216;
constexpr int HW = H * W;            // 311296 (divisible by 4)
constexpr int N  = B * HW;           // 9961472 elements in gt / weight_map
constexpr int NCHUNK  = N / 4;       // 2490368 float4 chunks
constexpr int BLOCKSZ = 256;
constexpr int GRID    = 1024;        // 4 blocks/CU; 9.5 chunks/thread (steady state)
constexpr int CSTRIDE = GRID * BLOCKSZ;   // 262144
constexpr int NSLOT   = 16;

// R13 design. R6-R12 matrix: depth-2/3/4, conditional vs straight-line,
// register vs LDS-DMA pipelines, 16 vs 32 waves/CU, nt vs cached — ALL land
// 47-61 us, and L3-resident dispatches (hbm_bytes~0) run at the SAME speed
// as 58MB-HBM ones. Conclusion: ~2.5 TB/s (310 GB/s/XCD) is a read-return
// service ceiling for this pattern, not a kernel-structure artifact. So:
// (1) revert seg to the best-measured config (R0: nt loads, depth-3
// conditional rotation, GRID=1024 — nt worth ~5-7us vs cached, L1-thrash
// avoidance); (2) the one untouched lever: fold finalize into the main
// kernel via last-block-done, removing one dispatch + one launch gap.
// Cross-XCD correctness (G16): partials published with agent-scope atomic
// stores (bypass non-coherent per-XCD L2), counter bump is acq_rel agent
// scope, last block reads partials with agent-scope atomic loads. Counter
// zeroed by a 4-byte hipMemsetAsync (stream-ordered, graph-capturable —
// the harness itself enqueues hipMemsetAsync).

typedef float vfloat4 __attribute__((ext_vector_type(4)));
typedef int   vint4   __attribute__((ext_vector_type(4)));

__device__ __forceinline__ void load3(const float* __restrict__ pred,
                                      const float* __restrict__ gt,
                                      const int*   __restrict__ wm,
                                      int c, vfloat4& p, vfloat4& g, vint4& w)
{
    const int i0 = c * 4;            // flat element index
    const int b  = i0 / HW;          // batch (magic-mul by compiler)
    // nt: best-measured config (R0/R5: L1 bypass avoids 3-stream thrash).
    p = __builtin_nontemporal_load((const vfloat4*)(pred + (i0 + b * HW)));
    g = __builtin_nontemporal_load((const vfloat4*)(gt + i0));
    w = __builtin_nontemporal_load((const vint4*)(wm + i0));
}

__device__ __forceinline__ void accum(const vfloat4& p, const vfloat4& g,
                                      const vint4& w, float* sum, int* cnt)
{
    const float e0 = p.x - g.x, e1 = p.y - g.y;
    const float e2 = p.z - g.z, e3 = p.w - g.w;
    const float s0 = e0 * e0, s1 = e1 * e1, s2 = e2 * e2, s3 = e3 * e3;
#pragma unroll
    for (int j = 0; j < 8; ++j) {
        const int bin = j + 1;
        sum[j] += (w.x == bin) ? s0 : 0.f;
        cnt[j] += (w.x == bin) ? 1 : 0;
        sum[j] += (w.y == bin) ? s1 : 0.f;
        cnt[j] += (w.y == bin) ? 1 : 0;
        sum[j] += (w.z == bin) ? s2 : 0.f;
        cnt[j] += (w.z == bin) ? 1 : 0;
        sum[j] += (w.w == bin) ? s3 : 0.f;
        cnt[j] += (w.w == bin) ? 1 : 0;
    }
}

__global__ __launch_bounds__(BLOCKSZ, 4) void seg_mse_kernel(
    const float* __restrict__ pred,
    const float* __restrict__ gt,
    const int*   __restrict__ wm,
    float* __restrict__ part,
    int*   __restrict__ counter,
    float* __restrict__ out)
{
    float sum[8] = {0.f, 0.f, 0.f, 0.f, 0.f, 0.f, 0.f, 0.f};
    int   cnt[8] = {0, 0, 0, 0, 0, 0, 0, 0};

    const int start = blockIdx.x * BLOCKSZ + threadIdx.x;

    // Depth-3 rotated pipeline (exact R0 structure, best measured: ~40-47us).
    vfloat4 p0, g0, p1, g1, p2, g2;
    vint4   w0, w1, w2;
    load3(pred, gt, wm, start,               p0, g0, w0);
    load3(pred, gt, wm, start + CSTRIDE,     p1, g1, w1);
    load3(pred, gt, wm, start + 2 * CSTRIDE, p2, g2, w2);
    int next = start + 3 * CSTRIDE;

    while (true) {
        accum(p0, g0, w0, sum, cnt);
        if (next < NCHUNK) { load3(pred, gt, wm, next, p0, g0, w0); next += CSTRIDE; }
        else { accum(p1, g1, w1, sum, cnt); accum(p2, g2, w2, sum, cnt); break; }

        accum(p1, g1, w1, sum, cnt);
        if (next < NCHUNK) { load3(pred, gt, wm, next, p1, g1, w1); next += CSTRIDE; }
        else { accum(p2, g2, w2, sum, cnt); accum(p0, g0, w0, sum, cnt); break; }

        accum(p2, g2, w2, sum, cnt);
        if (next < NCHUNK) { load3(pred, gt, wm, next, p2, g2, w2); next += CSTRIDE; }
        else { accum(p0, g0, w0, sum, cnt); accum(p1, g1, w1, sum, cnt); break; }
    }

    // wave (64-lane) butterfly reduction of all 16 partials
    float fcnt[8];
#pragma unroll
    for (int j = 0; j < 8; ++j) fcnt[j] = (float)cnt[j];
#pragma unroll
    for (int j = 0; j < 8; ++j) {
#pragma unroll
        for (int off = 32; off > 0; off >>= 1) {
            sum[j]  += __shfl_down(sum[j], off);
            fcnt[j] += __shfl_down(fcnt[j], off);
        }
    }

    // cross-wave reduction in LDS (256 threads = 4 waves)
    __shared__ float lsum[4][8];
    __shared__ float lcnt[4][8];
    const int wave = threadIdx.x >> 6;
    const int lane = threadIdx.x & 63;
    if (lane == 0) {
#pragma unroll
        for (int j = 0; j < 8; ++j) {
            lsum[wave][j] = sum[j];
            lcnt[wave][j] = fcnt[j];
        }
    }
    __syncthreads();

    // Publish 16 partials with agent-scope stores (bypass non-coherent
    // per-XCD L2 so the last block can read them — G16).
    if (threadIdx.x < 8) {
        const int j = threadIdx.x;
        __hip_atomic_store(&part[blockIdx.x * NSLOT + j],
                           lsum[0][j] + lsum[1][j] + lsum[2][j] + lsum[3][j],
                           __ATOMIC_RELAXED, __HIP_MEMORY_SCOPE_AGENT);
    } else if (threadIdx.x < 16) {
        const int j = threadIdx.x - 8;
        __hip_atomic_store(&part[blockIdx.x * NSLOT + 8 + j],
                           lcnt[0][j] + lcnt[1][j] + lcnt[2][j] + lcnt[3][j],
                           __ATOMIC_RELAXED, __HIP_MEMORY_SCOPE_AGENT);
    }
    __syncthreads();   // drains the stores (vmcnt) before the counter bump

    // Last-block-done: one acq_rel counter bump per block.
    __shared__ int lastflag;
    if (threadIdx.x == 0) {
        __threadfence();
        const int prev = __hip_atomic_fetch_add(counter, 1, __ATOMIC_ACQ_REL,
                                                __HIP_MEMORY_SCOPE_AGENT);
        lastflag = (prev == GRID - 1) ? 1 : 0;
    }
    __syncthreads();
    if (lastflag == 0) return;

    // ---- merged finalize (one block, 256 threads) ----
    const int tid = threadIdx.x;
    const int j   = tid & 15;        // slot
    const int g   = tid >> 4;        // group 0..15
    float v = 0.f;
#pragma unroll
    for (int i = 0; i < GRID / 16; ++i) {   // 64 agent-scope loads/thread
        v += __hip_atomic_load(&part[(g + 16 * i) * NSLOT + j],
                               __ATOMIC_RELAXED, __HIP_MEMORY_SCOPE_AGENT);
    }
    __shared__ float wsum2[16][16];
    wsum2[g][j] = v;
    __syncthreads();

    __shared__ float fin[16];
    if (tid < 16) {
        float t = 0.f;
#pragma unroll
        for (int g2 = 0; g2 < 16; ++g2) t += wsum2[g2][tid];
        fin[tid] = t;
    }
    __syncthreads();

    if (tid == 0) {
        float total = 0.f;
#pragma unroll
        for (int j2 = 0; j2 < 8; ++j2) {
            total += fin[j2] / fmaxf(fin[8 + j2], 1.f);
        }
        out[0] = total * (1.f / 8.f);
    }
}

extern "C" void kernel_launch(void* const* d_in, const int* in_sizes, int n_in,
                              void* d_out, int out_size, void* d_ws, size_t ws_size,
                              hipStream_t stream)
{
    const float* pred = (const float*)d_in[0];  // [32,2,256,1216] f32
    const float* gt   = (const float*)d_in[1];  // [32,1,256,1216] f32
    const int*   wm   = (const int*)d_in[2];    // [32,1,256,1216] i32
    float* part    = (float*)d_ws;                        // GRID*16 floats = 64 KB
    int*   counter = (int*)((char*)d_ws + GRID * NSLOT * sizeof(float));

    // Zero the arrival counter (ws is poisoned by the harness each iter).
    // Stream-ordered + graph-capturable; 4 bytes.
    hipMemsetAsync(counter, 0, sizeof(int), stream);
    seg_mse_kernel<<<GRID, BLOCKSZ, 0, stream>>>(pred, gt, wm, part, counter,
                                                 (float*)d_out);
}